// Round 8
// baseline (241.866 us; speedup 1.0000x reference)
//
#include <hip/hip_runtime.h>
#include <cstdint>
#include <cstddef>

#define B_   16
#define L_   8192
#define D_   256
#define NB_  8
#define NCHB 16    // chunks per batch row (512 tokens each); 256 blocks = 1/CU

// ws offsets (floats)
static const long OFF_QK   = 0;      // 2048
static const long OFF_QB   = 2048;   // 8
static const long OFF_PART = 4096;   // 2048 tasks * 2048 floats
static const long PART_FLOATS = 2048L * 2048;
static const long OFF_PSE  = OFF_PART + PART_FLOATS;  // 2048 * 8

// ---------------------------------------------------------------- k_setup
// 8 blocks, block h: qk[h][e] = (sum_d q[h*32+d] * Wk[256+h*32+d][e]) / sqrt(32).
__global__ __launch_bounds__(256) void k_setup(const float* __restrict__ query,
                                               const float* __restrict__ W,
                                               const float* __restrict__ bias,
                                               float* __restrict__ ws) {
    __shared__ float q_s[256];
    int t = threadIdx.x;
    int h = blockIdx.x;
    float acc = bias[t];
    const float* wr = W + (long)t * 256;
    #pragma unroll 8
    for (int e = 0; e < 256; e += 4) {
        float4 qv = *(const float4*)(query + e);
        float4 wv = *(const float4*)(wr + e);
        acc += qv.x * wv.x + qv.y * wv.y + qv.z * wv.z + qv.w * wv.w;
    }
    q_s[t] = acc;
    __syncthreads();
    const float rs = 0.17677669529663687f; // 1/sqrt(32)
    float s = 0.f;
    #pragma unroll 8
    for (int d = 0; d < 32; ++d) {
        int r = 256 + h * 32 + d;
        s += q_s[h * 32 + d] * W[(long)r * 256 + t];
    }
    ws[OFF_QK + h * 256 + t] = s * rs;
    if (t < 64) {
        float v = (t < 32) ? q_s[h * 32 + t] * bias[256 + h * 32 + t] : 0.f;
        v += __shfl_down(v, 16);
        v += __shfl_down(v, 8);
        v += __shfl_down(v, 4);
        v += __shfl_down(v, 2);
        v += __shfl_down(v, 1);
        if (t == 0) ws[OFF_QB + h] = v * rs;
    }
}

// 3-step butterfly over low 3 lane bits: p0..p7 per-lane partials for h=0..7
// over this lane's 4 e's. Result: lane (g,ep) holds octet (32-e) sum for h=ep.
__device__ __forceinline__ float reduce_ep(float p0, float p1, float p2, float p3,
                                           float p4, float p5, float p6, float p7, int ep) {
    bool b1 = (ep & 1) != 0;
    float s0 = b1 ? p0 : p1, k0 = b1 ? p1 : p0;
    float s1 = b1 ? p2 : p3, k1 = b1 ? p3 : p2;
    float s2 = b1 ? p4 : p5, k2 = b1 ? p5 : p4;
    float s3 = b1 ? p6 : p7, k3 = b1 ? p7 : p6;
    float n0 = k0 + __shfl_xor(s0, 1);
    float n1 = k1 + __shfl_xor(s1, 1);
    float n2 = k2 + __shfl_xor(s2, 1);
    float n3 = k3 + __shfl_xor(s3, 1);
    bool b2 = (ep & 2) != 0;
    float t0s = b2 ? n0 : n1, t0k = b2 ? n1 : n0;
    float t1s = b2 ? n2 : n3, t1k = b2 ? n3 : n2;
    float m0 = t0k + __shfl_xor(t0s, 2);
    float m1 = t1k + __shfl_xor(t1s, 2);
    bool b4 = (ep & 4) != 0;
    float us = b4 ? m0 : m1, uk = b4 ? m1 : m0;
    return uk + __shfl_xor(us, 4);
}

// Async global->LDS, 16B per lane, no VGPR landing zone.
__device__ __forceinline__ void gld16(const float* g, float* l) {
    __builtin_amdgcn_global_load_lds(
        (const __attribute__((address_space(1))) void*)g,
        (__attribute__((address_space(3))) void*)l, 16, 0, 0);
}

// ---------------------------------------------------------------- k_main
// One block (512 thr) per (b, 512-token chunk); 256 blocks = 1/CU.
// Staging: double-buffered 64KB LDS window via global_load_lds, counted
// vmcnt(8), raw barriers (proven in r7: staging fully hidden).
// Scores (per window): wave widx -> tokens widx*8..+8. qk lives in REGISTERS
// (per-lane e4-slice, loaded once). Per token: 1 conflict-free b128 x-row read,
// 32 FMA, butterfly -> lanes 0-7 write w[t][h] = exp(score) to wls. No qk LDS
// traffic, no mask handling (invalid tokens are skipped in pool).
// Pool (per window): thread = (hp=widx>>1 -> heads 2hp,2hp+1; e-pair). Lane
// pre-loads w-pair + packed bid for ONE token; the 64-token loop broadcasts
// them via v_readlane (VALU, not DS). Per token per wave: 1 b64 x read +
// wave-uniform switch + 6 FMA. Invalid (bidm==8): skip.
__global__ __launch_bounds__(512) void k_main(const float* __restrict__ x,
                                              const unsigned char* __restrict__ mask,
                                              const int* __restrict__ bid,
                                              const float* __restrict__ ws,
                                              float* __restrict__ part,
                                              float* __restrict__ pse) {
    __shared__ alignas(16) float xt[2][16384];   // 2 x 64KB window
    __shared__ alignas(16) float wls[64][8];     // w[token][head]
    __shared__ int bidl[512];                    // packed: valid ? bid : 8

    const int tid  = threadIdx.x;
    const int lane = tid & 63;
    const int widx = tid >> 6;
    const int bI   = blockIdx.x >> 4;
    const int ch   = blockIdx.x & 15;

    // ---------------- prologue
    {
        // mask dtype detection: packed 0/1 bool bytes read as int32 give a word
        // > 1 with probability 1-8^-64; a genuine int32 0/1 mask never does.
        const int* mi = (const int*)mask;
        bool bytemode = __ballot((unsigned)mi[lane] > 1u) != 0ull;
        long gt = (long)bI * L_ + ch * 512 + tid;
        int valid = bytemode ? (mask[gt] != 0) : (mi[gt] != 0);
        bidl[tid] = valid ? bid[gt] : 8;
    }

    // qk fragment in registers: qk[h][lane*4 .. +4), h=0..7  (32 VGPR)
    float4 qk[8];
    #pragma unroll
    for (int h = 0; h < 8; ++h)
        qk[h] = *(const float4*)(ws + OFF_QK + h * 256 + lane * 4);
    const float qb = ws[OFF_QB + (lane & 7)];

    __syncthreads();   // bidl ready; before any staging barrier discipline

    const float* xg = x + (long)bI * (L_ * D_) + (long)ch * (512 * D_);

    float acc[8][4];   // [n][{h0e0,h0e1,h1e0,h1e1}]
    #pragma unroll
    for (int n = 0; n < 8; ++n) {
        #pragma unroll
        for (int j = 0; j < 4; ++j) acc[n][j] = 0.f;
    }
    float se0[8], se1[8];
    #pragma unroll
    for (int n = 0; n < 8; ++n) { se0[n] = 0.f; se1[n] = 0.f; }

    // stage window 0 -> buf 0
    {
        const float* gp = xg + tid * 4;
        float* lp = &xt[0][tid * 4];
        #pragma unroll
        for (int r = 0; r < 8; ++r) gld16(gp + r * 2048, lp + r * 2048);
    }

    const int hp   = widx >> 1;                 // head-pair: 2hp, 2hp+1
    const int eoff = (widx & 1) * 64 + lane;    // e-pair index 0..127

    for (int w = 0; w < 8; ++w) {
        const int bufI = w & 1;
        if (w < 7) {
            const float* gp = xg + (long)(w + 1) * 16384 + tid * 4;
            float* lp = &xt[bufI ^ 1][tid * 4];
            #pragma unroll
            for (int r = 0; r < 8; ++r) gld16(gp + r * 2048, lp + r * 2048);
            asm volatile("s_waitcnt vmcnt(8)" ::: "memory");  // window w landed
        } else {
            asm volatile("s_waitcnt vmcnt(0)" ::: "memory");
        }
        __builtin_amdgcn_s_barrier();   // B1: xt[bufI] visible

        const float* xw = &xt[bufI][0];

        // ---- scores: 8 tokens for this wave
        #pragma unroll
        for (int tkk = 0; tkk < 8; ++tkk) {
            const int t = widx * 8 + tkk;   // wave-uniform
            float4 xv = *(const float4*)(xw + t * 256 + lane * 4);
            float p0 = xv.x*qk[0].x + xv.y*qk[0].y + xv.z*qk[0].z + xv.w*qk[0].w;
            float p1 = xv.x*qk[1].x + xv.y*qk[1].y + xv.z*qk[1].z + xv.w*qk[1].w;
            float p2 = xv.x*qk[2].x + xv.y*qk[2].y + xv.z*qk[2].z + xv.w*qk[2].w;
            float p3 = xv.x*qk[3].x + xv.y*qk[3].y + xv.z*qk[3].z + xv.w*qk[3].w;
            float p4 = xv.x*qk[4].x + xv.y*qk[4].y + xv.z*qk[4].z + xv.w*qk[4].w;
            float p5 = xv.x*qk[5].x + xv.y*qk[5].y + xv.z*qk[5].z + xv.w*qk[5].w;
            float p6 = xv.x*qk[6].x + xv.y*qk[6].y + xv.z*qk[6].z + xv.w*qk[6].w;
            float p7 = xv.x*qk[7].x + xv.y*qk[7].y + xv.z*qk[7].z + xv.w*qk[7].w;
            float s = reduce_ep(p0, p1, p2, p3, p4, p5, p6, p7, lane & 7);
            s += __shfl_xor(s, 8);
            s += __shfl_xor(s, 16);
            s += __shfl_xor(s, 32);
            float wgt = __expf(s + qb);
            if (lane < 8) wls[t][lane] = wgt;
        }
        asm volatile("s_waitcnt lgkmcnt(0)" ::: "memory");
        __builtin_amdgcn_s_barrier();   // B2: wls visible

        // ---- pool: lane pre-loads token data, loop broadcasts via readlane
        {
            float2 wpair = *(const float2*)&wls[lane][2 * hp];  // token=lane
            int wlo = __float_as_int(wpair.x);
            int whi = __float_as_int(wpair.y);
            int bidv = bidl[w * 64 + lane];
            for (int t = 0; t < 64; ++t) {
                int n_t = __builtin_amdgcn_readlane(bidv, t);
                if (n_t >= 8) continue;
                float wt0 = __uint_as_float(__builtin_amdgcn_readlane(wlo, t));
                float wt1 = __uint_as_float(__builtin_amdgcn_readlane(whi, t));
                float2 xv = *(const float2*)(xw + t * 256 + eoff * 2);
                bool sel = (tid & 127) == 0;
                #define POOL_ARM(N)                                               \
                    { acc[N][0] += wt0 * xv.x; acc[N][1] += wt0 * xv.y;            \
                      acc[N][2] += wt1 * xv.x; acc[N][3] += wt1 * xv.y;            \
                      if (sel) { se0[N] += wt0; se1[N] += wt1; } }
                switch (n_t) {
                    case 0: POOL_ARM(0); break;
                    case 1: POOL_ARM(1); break;
                    case 2: POOL_ARM(2); break;
                    case 3: POOL_ARM(3); break;
                    case 4: POOL_ARM(4); break;
                    case 5: POOL_ARM(5); break;
                    case 6: POOL_ARM(6); break;
                    default: POOL_ARM(7); break;
                }
                #undef POOL_ARM
            }
        }
        __builtin_amdgcn_s_barrier();   // B3: pool(w) done before xt[bufI] reuse
    }

    // ---------------- epilogue: one task per (block,n); disjoint (h,e) tiles
    const int blk = blockIdx.x;
    #pragma unroll
    for (int n = 0; n < 8; ++n) {
        long tb = (long)(blk * 8 + n) * 2048;
        float2 v01 = make_float2(acc[n][0], acc[n][1]);
        float2 v23 = make_float2(acc[n][2], acc[n][3]);
        *(float2*)&part[tb + (2 * hp) * 256 + 2 * eoff]     = v01;
        *(float2*)&part[tb + (2 * hp + 1) * 256 + 2 * eoff] = v23;
        if ((tid & 127) == 0) {
            pse[(long)(blk * 8 + n) * 8 + 2 * hp]     = se0[n];
            pse[(long)(blk * 8 + n) * 8 + 2 * hp + 1] = se1[n];
        }
    }
}

// ---------------------------------------------------------------- k_epi
// One block per (n,b): reduce the 16 chunk-partials (fixed order), normalize,
// wv-project, out-project, LayerNorm, zero empty backends, write out[b][n][:].
__global__ __launch_bounds__(256) void k_epi(const float* __restrict__ part,
                                             const float* __restrict__ pse,
                                             const float* __restrict__ W,
                                             const float* __restrict__ ib,
                                             const float* __restrict__ Wo,
                                             const float* __restrict__ ob,
                                             const float* __restrict__ gamma,
                                             const float* __restrict__ beta,
                                             float* __restrict__ out) {
    __shared__ float pn[2048];
    __shared__ float ses[8];
    __shared__ float ctx_s[256];
    __shared__ float r1[4], r2[4];
    int n = blockIdx.x & 7, b = blockIdx.x >> 3;
    int t = threadIdx.x;
    if (t < 8) {
        float s = 0.f;
        for (int chv = 0; chv < NCHB; ++chv)
            s += pse[(long)(b * 128 + chv * 8 + n) * 8 + t];
        ses[t] = s;
    }
    __syncthreads();
    bool has = ses[0] > 0.f;
    for (int j = 0; j < 8; ++j) {
        int idx = j * 256 + t;
        int h = idx >> 8;
        float s = 0.f;
        for (int chv = 0; chv < NCHB; ++chv)
            s += part[(long)(b * 128 + chv * 8 + n) * 2048 + idx];
        pn[idx] = has ? s / ses[h] : 0.f;
    }
    __syncthreads();
    int h = t >> 5;
    float c = ib[512 + t];
    {
        const float* wr = W + (long)(512 + t) * 256;
        const float* ph = pn + h * 256;
        for (int e = 0; e < 256; e += 4) {
            float4 wv4 = *(const float4*)(wr + e);
            float4 pv4 = *(const float4*)(ph + e);
            c += wv4.x * pv4.x + wv4.y * pv4.y + wv4.z * pv4.z + wv4.w * pv4.w;
        }
    }
    ctx_s[t] = c;
    __syncthreads();
    float o = ob[t];
    {
        const float* wr = Wo + (long)t * 256;
        for (int d = 0; d < 256; d += 4) {
            float4 wv4 = *(const float4*)(wr + d);
            float4 cv4 = *(const float4*)(ctx_s + d);
            o += wv4.x * cv4.x + wv4.y * cv4.y + wv4.z * cv4.z + wv4.w * cv4.w;
        }
    }
    float s1 = o, s2 = o * o;
    #pragma unroll
    for (int off = 32; off >= 1; off >>= 1) {
        s1 += __shfl_down(s1, off);
        s2 += __shfl_down(s2, off);
    }
    if ((t & 63) == 0) { r1[t >> 6] = s1; r2[t >> 6] = s2; }
    __syncthreads();
    float S1 = r1[0] + r1[1] + r1[2] + r1[3];
    float S2 = r2[0] + r2[1] + r2[2] + r2[3];
    float mu = S1 * (1.f / 256.f);
    float var = S2 * (1.f / 256.f) - mu * mu;
    float rr = rsqrtf(var + 1e-5f);
    float res = ((o - mu) * rr * gamma[t] + beta[t]) * (has ? 1.f : 0.f);
    out[((long)b * 8 + n) * 256 + t] = res;
}

// ---------------------------------------------------------------- launch
extern "C" void kernel_launch(void* const* d_in, const int* in_sizes, int n_in,
                              void* d_out, int out_size, void* d_ws, size_t ws_size,
                              hipStream_t stream) {
    const float* x     = (const float*)d_in[0];
    const float* query = (const float*)d_in[1];
    const float* W     = (const float*)d_in[2];
    const float* ib    = (const float*)d_in[3];
    const float* Wo    = (const float*)d_in[4];
    const float* ob    = (const float*)d_in[5];
    const float* gamma = (const float*)d_in[6];
    const float* beta  = (const float*)d_in[7];
    const unsigned char* mask = (const unsigned char*)d_in[8];
    const int* bid     = (const int*)d_in[9];
    float* out = (float*)d_out;
    float* ws  = (float*)d_ws;

    float* part = ws + OFF_PART;
    float* pse  = ws + OFF_PSE;

    k_setup<<<8, 256, 0, stream>>>(query, W, ib, ws);
    k_main<<<B_ * NCHB, 512, 0, stream>>>(x, mask, bid, ws, part, pse);
    k_epi<<<B_ * NB_, 256, 0, stream>>>(part, pse, W, ib, Wo, ob, gamma, beta, out);
}

// Round 9
// 146.775 us; speedup vs baseline: 1.6479x; 1.6479x over previous
//
#include <hip/hip_runtime.h>
#include <cstdint>
#include <cstddef>

#define B_   16
#define L_   8192
#define D_   256
#define NB_  8
#define NCHB 16    // 512-token chunks per batch row; grid = 256 blocks

typedef __attribute__((ext_vector_type(8))) short bf16x8;
typedef __attribute__((ext_vector_type(16))) float f32x16;

// ws offsets (floats) — identical to r7/r8 (proven with k_epi)
static const long OFF_QK   = 0;      // 2048
static const long OFF_QB   = 2048;   // 8
static const long OFF_PART = 4096;   // 2048 tasks * 2048 floats
static const long PART_FLOATS = 2048L * 2048;
static const long OFF_PSE  = OFF_PART + PART_FLOATS;  // 2048 * 8

// ---------------------------------------------------------------- k_setup (unchanged)
__global__ __launch_bounds__(256) void k_setup(const float* __restrict__ query,
                                               const float* __restrict__ W,
                                               const float* __restrict__ bias,
                                               float* __restrict__ ws) {
    __shared__ float q_s[256];
    int t = threadIdx.x;
    int h = blockIdx.x;
    float acc = bias[t];
    const float* wr = W + (long)t * 256;
    #pragma unroll 8
    for (int e = 0; e < 256; e += 4) {
        float4 qv = *(const float4*)(query + e);
        float4 wv = *(const float4*)(wr + e);
        acc += qv.x * wv.x + qv.y * wv.y + qv.z * wv.z + qv.w * wv.w;
    }
    q_s[t] = acc;
    __syncthreads();
    const float rs = 0.17677669529663687f; // 1/sqrt(32)
    float s = 0.f;
    #pragma unroll 8
    for (int d = 0; d < 32; ++d) {
        int r = 256 + h * 32 + d;
        s += q_s[h * 32 + d] * W[(long)r * 256 + t];
    }
    ws[OFF_QK + h * 256 + t] = s * rs;
    if (t < 64) {
        float v = (t < 32) ? q_s[h * 32 + t] * bias[256 + h * 32 + t] : 0.f;
        v += __shfl_down(v, 16);
        v += __shfl_down(v, 8);
        v += __shfl_down(v, 4);
        v += __shfl_down(v, 2);
        v += __shfl_down(v, 1);
        if (t == 0) ws[OFF_QB + h] = v * rs;
    }
}

// 3-step butterfly over low 3 lane bits (r8-proven).
__device__ __forceinline__ float reduce_ep(float p0, float p1, float p2, float p3,
                                           float p4, float p5, float p6, float p7, int ep) {
    bool b1 = (ep & 1) != 0;
    float s0 = b1 ? p0 : p1, k0 = b1 ? p1 : p0;
    float s1 = b1 ? p2 : p3, k1 = b1 ? p3 : p2;
    float s2 = b1 ? p4 : p5, k2 = b1 ? p5 : p4;
    float s3 = b1 ? p6 : p7, k3 = b1 ? p7 : p6;
    float n0 = k0 + __shfl_xor(s0, 1);
    float n1 = k1 + __shfl_xor(s1, 1);
    float n2 = k2 + __shfl_xor(s2, 1);
    float n3 = k3 + __shfl_xor(s3, 1);
    bool b2 = (ep & 2) != 0;
    float t0s = b2 ? n0 : n1, t0k = b2 ? n1 : n0;
    float t1s = b2 ? n2 : n3, t1k = b2 ? n3 : n2;
    float m0 = t0k + __shfl_xor(t0s, 2);
    float m1 = t1k + __shfl_xor(t1s, 2);
    bool b4 = (ep & 4) != 0;
    float us = b4 ? m0 : m1, uk = b4 ? m1 : m0;
    return uk + __shfl_xor(us, 4);
}

// RNE f32 -> bf16 pair pack (bit-exact for finite values; no intrinsic dependency).
__device__ __forceinline__ unsigned pack_bf16(float lo, float hi) {
    unsigned ul = __float_as_uint(lo);
    unsigned uh = __float_as_uint(hi);
    ul = (ul + 0x7fffu + ((ul >> 16) & 1u)) >> 16;
    uh = (uh + 0x7fffu + ((uh >> 16) & 1u)) >> 16;
    return ul | (uh << 16);
}

union FragCast { uint4 u4; bf16x8 b8; };

// ---------------------------------------------------------------- k_main
// One block (1024 thr = 16 waves, 4/SIMD) per (b, 512-token chunk).
// No x LDS staging. Per 64-token window:
//  P1 scores: wave widx -> 4 tokens; x rows read GLOBAL coalesced (the HBM
//     pass); qk in registers; butterfly -> wls[64][8] (fp32).
//  P2 A-build: waves 0..7 = (ghb=widx&1, ks=widx>>1): P[(n,h),t] =
//     (bid==n)?bf16(w):0 packed into A-frag layout in LDS; row-sums -> se.
//  P3 MFMA: wave (gh=widx>>3, eq=widx&7) owns C-tile rows gh*32..+31 (nh),
//     cols eq*32..+31 (e). B-frags: x re-read from GLOBAL (L2-hot, loads
//     issued at window top so latency hides under scores). 4 K-steps of
//     v_mfma_f32_32x32x16_bf16; acc persists in AGPRs across all 8 windows.
// Fragment maps (32x32x16): A: row=lane&31, k=8*(lane>>5)+j (j = consecutive
// shorts); B: col=lane&31, same k map; D: col=lane&31,
// row=(reg&3)+8*(reg>>2)+4*(lane>>5)  [C/D HW-verified].
__global__ __launch_bounds__(1024) void k_main(const float* __restrict__ x,
                                               const unsigned char* __restrict__ mask,
                                               const int* __restrict__ bid,
                                               const float* __restrict__ ws,
                                               float* __restrict__ part,
                                               float* __restrict__ pse) {
    __shared__ float wls[64][8];
    __shared__ int bidl[512];
    __shared__ alignas(16) unsigned Alds[2][4][64][4];  // [gh][ks][lane][dword]
    __shared__ float seLds[8][64];

    const int tid  = threadIdx.x;
    const int lane = tid & 63;
    const int widx = tid >> 6;         // 0..15
    const int bI   = blockIdx.x >> 4;
    const int ch   = blockIdx.x & 15;

    // ---------------- prologue
    {
        // mask dtype detection: packed 0/1 bool bytes read as int32 give a word
        // > 1 with probability 1-8^-64; a genuine int32 0/1 mask never does.
        const int* mi = (const int*)mask;
        bool bytemode = __ballot((unsigned)mi[lane] > 1u) != 0ull;
        if (tid < 512) {
            long gt = (long)bI * L_ + ch * 512 + tid;
            int valid = bytemode ? (mask[gt] != 0) : (mi[gt] != 0);
            bidl[tid] = valid ? bid[gt] : 8;
        }
    }
    float4 qk[8];
    #pragma unroll
    for (int h = 0; h < 8; ++h)
        qk[h] = *(const float4*)(ws + OFF_QK + h * 256 + lane * 4);
    const float qb = ws[OFF_QB + (lane & 7)];
    __syncthreads();

    const float* xc = x + (long)bI * (L_ * D_) + (long)ch * (512 * D_);

    const int gh  = widx >> 3;      // C row-group (nh 32-block)
    const int eq  = widx & 7;       // C col-tile
    const int e0  = eq * 32;
    const int m32 = lane & 31;
    const int kh  = lane >> 5;

    f32x16 acc;
    #pragma unroll
    for (int r = 0; r < 16; ++r) acc[r] = 0.f;
    float rowsum = 0.f;   // A-build waves only

    for (int w = 0; w < 8; ++w) {
        const float* xw = xc + w * (64 * D_);

        // ---- issue B loads for this window (consumed in P3; latency hides
        //      under scores compute; drained by bar1's vmcnt(0))
        float bstage[4][8];
        #pragma unroll
        for (int ks = 0; ks < 4; ++ks) {
            #pragma unroll
            for (int j = 0; j < 8; ++j) {
                int t = ks * 16 + kh * 8 + j;
                bstage[ks][j] = xw[t * 256 + e0 + m32];
            }
        }

        // ---- P1: scores, 4 tokens per wave
        #pragma unroll
        for (int q = 0; q < 4; ++q) {
            int t = widx * 4 + q;
            float4 xv = *(const float4*)(xw + t * 256 + lane * 4);
            float p0 = xv.x*qk[0].x + xv.y*qk[0].y + xv.z*qk[0].z + xv.w*qk[0].w;
            float p1 = xv.x*qk[1].x + xv.y*qk[1].y + xv.z*qk[1].z + xv.w*qk[1].w;
            float p2 = xv.x*qk[2].x + xv.y*qk[2].y + xv.z*qk[2].z + xv.w*qk[2].w;
            float p3 = xv.x*qk[3].x + xv.y*qk[3].y + xv.z*qk[3].z + xv.w*qk[3].w;
            float p4 = xv.x*qk[4].x + xv.y*qk[4].y + xv.z*qk[4].z + xv.w*qk[4].w;
            float p5 = xv.x*qk[5].x + xv.y*qk[5].y + xv.z*qk[5].z + xv.w*qk[5].w;
            float p6 = xv.x*qk[6].x + xv.y*qk[6].y + xv.z*qk[6].z + xv.w*qk[6].w;
            float p7 = xv.x*qk[7].x + xv.y*qk[7].y + xv.z*qk[7].z + xv.w*qk[7].w;
            float s = reduce_ep(p0, p1, p2, p3, p4, p5, p6, p7, lane & 7);
            s += __shfl_xor(s, 8);
            s += __shfl_xor(s, 16);
            s += __shfl_xor(s, 32);
            float wgt = __expf(s + qb);
            if (lane < 8) wls[t][lane] = wgt;
        }
        __syncthreads();   // bar1: wls ready

        // ---- P2: A-build (waves 0..7), one (gh-group, K-step) each
        if (widx < 8) {
            int ghb = widx & 1, ks = widx >> 1;
            int nh = ghb * 32 + m32;
            int nn = nh >> 3, hh = nh & 7;
            unsigned pk[4];
            #pragma unroll
            for (int r = 0; r < 4; ++r) {
                int t0 = ks * 16 + kh * 8 + 2 * r;
                float f0 = (bidl[w * 64 + t0] == nn)     ? wls[t0][hh]     : 0.f;
                float f1 = (bidl[w * 64 + t0 + 1] == nn) ? wls[t0 + 1][hh] : 0.f;
                rowsum += f0 + f1;
                pk[r] = pack_bf16(f0, f1);
            }
            *(uint4*)&Alds[ghb][ks][lane][0] = make_uint4(pk[0], pk[1], pk[2], pk[3]);
        }
        __syncthreads();   // bar2: Alds ready

        // ---- P3: 4 MFMA K-steps
        #pragma unroll
        for (int ks = 0; ks < 4; ++ks) {
            FragCast a, b;
            a.u4 = *(const uint4*)&Alds[gh][ks][lane][0];
            b.u4 = make_uint4(pack_bf16(bstage[ks][0], bstage[ks][1]),
                              pack_bf16(bstage[ks][2], bstage[ks][3]),
                              pack_bf16(bstage[ks][4], bstage[ks][5]),
                              pack_bf16(bstage[ks][6], bstage[ks][7]));
            acc = __builtin_amdgcn_mfma_f32_32x32x16_bf16(a.b8, b.b8, acc, 0, 0, 0);
        }
        __syncthreads();   // bar3: wls/Alds consumed before next window
    }

    // ---------------- epilogue: D -> part
    #pragma unroll
    for (int r = 0; r < 16; ++r) {
        int m  = (r & 3) + 8 * (r >> 2) + 4 * kh;
        int nh = gh * 32 + m;
        int nn = nh >> 3, hh = nh & 7;
        part[((long)(blockIdx.x * 8 + nn)) * 2048 + hh * 256 + e0 + m32] = acc[r];
    }
    // se: gather A-build row-sums
    if (widx < 8) seLds[widx][lane] = rowsum;
    __syncthreads();
    if (widx == 0) {
        int ghb = lane >> 5, m = lane & 31;
        float s = 0.f;
        #pragma unroll
        for (int ks = 0; ks < 4; ++ks)
            s += seLds[ks * 2 + ghb][m] + seLds[ks * 2 + ghb][m + 32];
        int nn = lane >> 3, hh = lane & 7;
        pse[((long)(blockIdx.x * 8 + nn)) * 8 + hh] = s;
    }
}

// ---------------------------------------------------------------- k_epi (unchanged)
__global__ __launch_bounds__(256) void k_epi(const float* __restrict__ part,
                                             const float* __restrict__ pse,
                                             const float* __restrict__ W,
                                             const float* __restrict__ ib,
                                             const float* __restrict__ Wo,
                                             const float* __restrict__ ob,
                                             const float* __restrict__ gamma,
                                             const float* __restrict__ beta,
                                             float* __restrict__ out) {
    __shared__ float pn[2048];
    __shared__ float ses[8];
    __shared__ float ctx_s[256];
    __shared__ float r1[4], r2[4];
    int n = blockIdx.x & 7, b = blockIdx.x >> 3;
    int t = threadIdx.x;
    if (t < 8) {
        float s = 0.f;
        for (int chv = 0; chv < NCHB; ++chv)
            s += pse[(long)(b * 128 + chv * 8 + n) * 8 + t];
        ses[t] = s;
    }
    __syncthreads();
    bool has = ses[0] > 0.f;
    for (int j = 0; j < 8; ++j) {
        int idx = j * 256 + t;
        int h = idx >> 8;
        float s = 0.f;
        for (int chv = 0; chv < NCHB; ++chv)
            s += part[(long)(b * 128 + chv * 8 + n) * 2048 + idx];
        pn[idx] = has ? s / ses[h] : 0.f;
    }
    __syncthreads();
    int h = t >> 5;
    float c = ib[512 + t];
    {
        const float* wr = W + (long)(512 + t) * 256;
        const float* ph = pn + h * 256;
        for (int e = 0; e < 256; e += 4) {
            float4 wv4 = *(const float4*)(wr + e);
            float4 pv4 = *(const float4*)(ph + e);
            c += wv4.x * pv4.x + wv4.y * pv4.y + wv4.z * pv4.z + wv4.w * pv4.w;
        }
    }
    ctx_s[t] = c;
    __syncthreads();
    float o = ob[t];
    {
        const float* wr = Wo + (long)t * 256;
        for (int d = 0; d < 256; d += 4) {
            float4 wv4 = *(const float4*)(wr + d);
            float4 cv4 = *(const float4*)(ctx_s + d);
            o += wv4.x * cv4.x + wv4.y * cv4.y + wv4.z * cv4.z + wv4.w * cv4.w;
        }
    }
    float s1 = o, s2 = o * o;
    #pragma unroll
    for (int off = 32; off >= 1; off >>= 1) {
        s1 += __shfl_down(s1, off);
        s2 += __shfl_down(s2, off);
    }
    if ((t & 63) == 0) { r1[t >> 6] = s1; r2[t >> 6] = s2; }
    __syncthreads();
    float S1 = r1[0] + r1[1] + r1[2] + r1[3];
    float S2 = r2[0] + r2[1] + r2[2] + r2[3];
    float mu = S1 * (1.f / 256.f);
    float var = S2 * (1.f / 256.f) - mu * mu;
    float rr = rsqrtf(var + 1e-5f);
    float res = ((o - mu) * rr * gamma[t] + beta[t]) * (has ? 1.f : 0.f);
    out[((long)b * 8 + n) * 256 + t] = res;
}

// ---------------------------------------------------------------- launch
extern "C" void kernel_launch(void* const* d_in, const int* in_sizes, int n_in,
                              void* d_out, int out_size, void* d_ws, size_t ws_size,
                              hipStream_t stream) {
    const float* x     = (const float*)d_in[0];
    const float* query = (const float*)d_in[1];
    const float* W     = (const float*)d_in[2];
    const float* ib    = (const float*)d_in[3];
    const float* Wo    = (const float*)d_in[4];
    const float* ob    = (const float*)d_in[5];
    const float* gamma = (const float*)d_in[6];
    const float* beta  = (const float*)d_in[7];
    const unsigned char* mask = (const unsigned char*)d_in[8];
    const int* bid     = (const int*)d_in[9];
    float* out = (float*)d_out;
    float* ws  = (float*)d_ws;

    float* part = ws + OFF_PART;
    float* pse  = ws + OFF_PSE;

    k_setup<<<8, 256, 0, stream>>>(query, W, ib, ws);
    k_main<<<B_ * NCHB, 1024, 0, stream>>>(x, mask, bid, ws, part, pse);
    k_epi<<<B_ * NB_, 256, 0, stream>>>(part, pse, W, ib, Wo, ob, gamma, beta, out);
}

// Round 10
// 85.709 us; speedup vs baseline: 2.8220x; 1.7125x over previous
//
#include <hip/hip_runtime.h>
#include <cstdint>
#include <cstddef>

#define B_   16
#define L_   8192
#define D_   256
#define NB_  8
#define NCHB 16    // 512-token chunks per batch row; grid = 256 blocks

typedef __attribute__((ext_vector_type(8))) short bf16x8;
typedef __attribute__((ext_vector_type(16))) float f32x16;

// ws offsets (floats) — identical to r7..r9 (proven with k_epi)
static const long OFF_QK   = 0;      // 2048
static const long OFF_QB   = 2048;   // 8
static const long OFF_PART = 4096;   // 2048 tasks * 2048 floats
static const long PART_FLOATS = 2048L * 2048;
static const long OFF_PSE  = OFF_PART + PART_FLOATS;  // 2048 * 8

// ---------------------------------------------------------------- k_setup (unchanged)
__global__ __launch_bounds__(256) void k_setup(const float* __restrict__ query,
                                               const float* __restrict__ W,
                                               const float* __restrict__ bias,
                                               float* __restrict__ ws) {
    __shared__ float q_s[256];
    int t = threadIdx.x;
    int h = blockIdx.x;
    float acc = bias[t];
    const float* wr = W + (long)t * 256;
    #pragma unroll 8
    for (int e = 0; e < 256; e += 4) {
        float4 qv = *(const float4*)(query + e);
        float4 wv = *(const float4*)(wr + e);
        acc += qv.x * wv.x + qv.y * wv.y + qv.z * wv.z + qv.w * wv.w;
    }
    q_s[t] = acc;
    __syncthreads();
    const float rs = 0.17677669529663687f; // 1/sqrt(32)
    float s = 0.f;
    #pragma unroll 8
    for (int d = 0; d < 32; ++d) {
        int r = 256 + h * 32 + d;
        s += q_s[h * 32 + d] * W[(long)r * 256 + t];
    }
    ws[OFF_QK + h * 256 + t] = s * rs;
    if (t < 64) {
        float v = (t < 32) ? q_s[h * 32 + t] * bias[256 + h * 32 + t] : 0.f;
        v += __shfl_down(v, 16);
        v += __shfl_down(v, 8);
        v += __shfl_down(v, 4);
        v += __shfl_down(v, 2);
        v += __shfl_down(v, 1);
        if (t == 0) ws[OFF_QB + h] = v * rs;
    }
}

// 3-step butterfly over low 3 lane bits (r8/r9-proven).
__device__ __forceinline__ float reduce_ep(float p0, float p1, float p2, float p3,
                                           float p4, float p5, float p6, float p7, int ep) {
    bool b1 = (ep & 1) != 0;
    float s0 = b1 ? p0 : p1, k0 = b1 ? p1 : p0;
    float s1 = b1 ? p2 : p3, k1 = b1 ? p3 : p2;
    float s2 = b1 ? p4 : p5, k2 = b1 ? p5 : p4;
    float s3 = b1 ? p6 : p7, k3 = b1 ? p7 : p6;
    float n0 = k0 + __shfl_xor(s0, 1);
    float n1 = k1 + __shfl_xor(s1, 1);
    float n2 = k2 + __shfl_xor(s2, 1);
    float n3 = k3 + __shfl_xor(s3, 1);
    bool b2 = (ep & 2) != 0;
    float t0s = b2 ? n0 : n1, t0k = b2 ? n1 : n0;
    float t1s = b2 ? n2 : n3, t1k = b2 ? n3 : n2;
    float m0 = t0k + __shfl_xor(t0s, 2);
    float m1 = t1k + __shfl_xor(t1s, 2);
    bool b4 = (ep & 4) != 0;
    float us = b4 ? m0 : m1, uk = b4 ? m1 : m0;
    return uk + __shfl_xor(us, 4);
}

// RNE f32 -> bf16 pair pack.
__device__ __forceinline__ unsigned pack_bf16(float lo, float hi) {
    unsigned ul = __float_as_uint(lo);
    unsigned uh = __float_as_uint(hi);
    ul = (ul + 0x7fffu + ((ul >> 16) & 1u)) >> 16;
    uh = (uh + 0x7fffu + ((uh >> 16) & 1u)) >> 16;
    return ul | (uh << 16);
}

union FragCast { uint4 u4; bf16x8 b8; };

// Async global->LDS, 16B per lane, no VGPR landing zone.
__device__ __forceinline__ void gld16(const float* g, float* l) {
    __builtin_amdgcn_global_load_lds(
        (const __attribute__((address_space(1))) void*)g,
        (__attribute__((address_space(3))) void*)l, 16, 0, 0);
}

// ---------------------------------------------------------------- k_main
// One block (1024 thr = 16 waves, 4/SIMD) per (b, 512-token chunk).
// x is read from HBM EXACTLY ONCE via global_load_lds into a double-buffered
// 64KB window (counted vmcnt(4): next window's 4 loads stay in flight across
// the compute barriers — r7-proven hiding). Per 64-token window:
//  P1 scores: wave widx -> 4 tokens; x row from LDS (wave-uniform row, lanes
//     span e -> conflict-free b128); qk in registers; butterfly -> wls[64][8].
//  P2 A-build (waves 0..7): P[(n,h),t]=(bid==n)?bf16(w):0 into A-frag LDS;
//     row-sums -> se.
//  P3 MFMA: wave (gh=widx>>3, eq=widx&7): A from LDS (b128), B = x[t][e0+m32]
//     from LDS (8xb32/K-step, banks=m32 -> conflict-free); 4 K-steps of
//     v_mfma_f32_32x32x16_bf16; acc persists in AGPRs across windows.
// Fragment maps as r9 (correctness-proven): A row=lane&31, k=8*(lane>>5)+j;
// B col=lane&31 same k; D col=lane&31, row=(r&3)+8*(r>>2)+4*(lane>>5).
__global__ __launch_bounds__(1024) void k_main(const float* __restrict__ x,
                                               const unsigned char* __restrict__ mask,
                                               const int* __restrict__ bid,
                                               const float* __restrict__ ws,
                                               float* __restrict__ part,
                                               float* __restrict__ pse) {
    __shared__ alignas(16) float xt[2][16384];          // 2 x 64KB window
    __shared__ float wls[64][8];
    __shared__ int bidl[512];
    __shared__ alignas(16) unsigned Alds[2][4][64][4];  // [gh][ks][lane][dword]
    __shared__ float seLds[8][64];

    const int tid  = threadIdx.x;
    const int lane = tid & 63;
    const int widx = tid >> 6;         // 0..15
    const int bI   = blockIdx.x >> 4;
    const int ch   = blockIdx.x & 15;

    // ---------------- prologue
    {
        // mask dtype detection: packed 0/1 bool bytes read as int32 give a word
        // > 1 with probability 1-8^-64; a genuine int32 0/1 mask never does.
        const int* mi = (const int*)mask;
        bool bytemode = __ballot((unsigned)mi[lane] > 1u) != 0ull;
        if (tid < 512) {
            long gt = (long)bI * L_ + ch * 512 + tid;
            int valid = bytemode ? (mask[gt] != 0) : (mi[gt] != 0);
            bidl[tid] = valid ? bid[gt] : 8;
        }
    }
    float4 qk[8];
    #pragma unroll
    for (int h = 0; h < 8; ++h)
        qk[h] = *(const float4*)(ws + OFF_QK + h * 256 + lane * 4);
    const float qb = ws[OFF_QB + (lane & 7)];
    // Keep-alive: force qk/qb loads to be issued & waited here, so the in-loop
    // vmcnt(N) counts ONLY the gld16 staging ops.
    #pragma unroll
    for (int h = 0; h < 8; ++h)
        asm volatile("" :: "v"(qk[h].x), "v"(qk[h].y), "v"(qk[h].z), "v"(qk[h].w));
    asm volatile("" :: "v"(qb));
    __syncthreads();   // full drain (compiler-inserted waitcnt) + barrier

    const float* xc = x + (long)bI * (L_ * D_) + (long)ch * (512 * D_);

    const int gh  = widx >> 3;      // C row-group (nh 32-block)
    const int eq  = widx & 7;       // C col-tile
    const int e0  = eq * 32;
    const int m32 = lane & 31;
    const int kh  = lane >> 5;

    f32x16 acc;
    #pragma unroll
    for (int r = 0; r < 16; ++r) acc[r] = 0.f;
    float rowsum = 0.f;   // A-build waves only

    // stage window 0 -> buf 0 (4 x 16B per thread = 64KB per block)
    {
        const float* gp = xc + tid * 4;
        #pragma unroll
        for (int r = 0; r < 4; ++r)
            gld16(gp + r * 4096, &xt[0][tid * 4 + r * 4096]);
    }

    for (int w = 0; w < 8; ++w) {
        const int bufI = w & 1;
        if (w < 7) {
            const float* gp = xc + (long)(w + 1) * 16384 + tid * 4;
            #pragma unroll
            for (int r = 0; r < 4; ++r)
                gld16(gp + r * 4096, &xt[bufI ^ 1][tid * 4 + r * 4096]);
            asm volatile("s_waitcnt vmcnt(4)" ::: "memory");  // window w landed
        } else {
            asm volatile("s_waitcnt vmcnt(0)" ::: "memory");
        }
        __builtin_amdgcn_s_barrier();   // B1: xt[bufI] visible to all waves

        const float* xw = &xt[bufI][0];

        // ---- P1: scores, 4 tokens per wave (conflict-free b128 from LDS)
        #pragma unroll
        for (int q = 0; q < 4; ++q) {
            int t = widx * 4 + q;   // wave-uniform
            float4 xv = *(const float4*)(xw + t * 256 + lane * 4);
            float p0 = xv.x*qk[0].x + xv.y*qk[0].y + xv.z*qk[0].z + xv.w*qk[0].w;
            float p1 = xv.x*qk[1].x + xv.y*qk[1].y + xv.z*qk[1].z + xv.w*qk[1].w;
            float p2 = xv.x*qk[2].x + xv.y*qk[2].y + xv.z*qk[2].z + xv.w*qk[2].w;
            float p3 = xv.x*qk[3].x + xv.y*qk[3].y + xv.z*qk[3].z + xv.w*qk[3].w;
            float p4 = xv.x*qk[4].x + xv.y*qk[4].y + xv.z*qk[4].z + xv.w*qk[4].w;
            float p5 = xv.x*qk[5].x + xv.y*qk[5].y + xv.z*qk[5].z + xv.w*qk[5].w;
            float p6 = xv.x*qk[6].x + xv.y*qk[6].y + xv.z*qk[6].z + xv.w*qk[6].w;
            float p7 = xv.x*qk[7].x + xv.y*qk[7].y + xv.z*qk[7].z + xv.w*qk[7].w;
            float s = reduce_ep(p0, p1, p2, p3, p4, p5, p6, p7, lane & 7);
            s += __shfl_xor(s, 8);
            s += __shfl_xor(s, 16);
            s += __shfl_xor(s, 32);
            float wgt = __expf(s + qb);
            if (lane < 8) wls[t][lane] = wgt;
        }
        asm volatile("s_waitcnt lgkmcnt(0)" ::: "memory");
        __builtin_amdgcn_s_barrier();   // B2: wls visible

        // ---- P2: A-build (waves 0..7), one (gh-group, K-step) each
        if (widx < 8) {
            int ghb = widx & 1, ks = widx >> 1;
            int nh = ghb * 32 + m32;
            int nn = nh >> 3, hh = nh & 7;
            unsigned pk[4];
            #pragma unroll
            for (int r = 0; r < 4; ++r) {
                int t0 = ks * 16 + kh * 8 + 2 * r;
                float f0 = (bidl[w * 64 + t0] == nn)     ? wls[t0][hh]     : 0.f;
                float f1 = (bidl[w * 64 + t0 + 1] == nn) ? wls[t0 + 1][hh] : 0.f;
                rowsum += f0 + f1;
                pk[r] = pack_bf16(f0, f1);
            }
            *(uint4*)&Alds[ghb][ks][lane][0] = make_uint4(pk[0], pk[1], pk[2], pk[3]);
        }
        asm volatile("s_waitcnt lgkmcnt(0)" ::: "memory");
        __builtin_amdgcn_s_barrier();   // B3: Alds ready

        // ---- P3: 4 MFMA K-steps; A b128 + B 8xb32 from LDS
        #pragma unroll
        for (int ks = 0; ks < 4; ++ks) {
            FragCast a, b;
            a.u4 = *(const uint4*)&Alds[gh][ks][lane][0];
            float b0 = xw[(ks * 16 + kh * 8 + 0) * 256 + e0 + m32];
            float b1 = xw[(ks * 16 + kh * 8 + 1) * 256 + e0 + m32];
            float b2 = xw[(ks * 16 + kh * 8 + 2) * 256 + e0 + m32];
            float b3 = xw[(ks * 16 + kh * 8 + 3) * 256 + e0 + m32];
            float b4 = xw[(ks * 16 + kh * 8 + 4) * 256 + e0 + m32];
            float b5 = xw[(ks * 16 + kh * 8 + 5) * 256 + e0 + m32];
            float b6 = xw[(ks * 16 + kh * 8 + 6) * 256 + e0 + m32];
            float b7 = xw[(ks * 16 + kh * 8 + 7) * 256 + e0 + m32];
            b.u4 = make_uint4(pack_bf16(b0, b1), pack_bf16(b2, b3),
                              pack_bf16(b4, b5), pack_bf16(b6, b7));
            acc = __builtin_amdgcn_mfma_f32_32x32x16_bf16(a.b8, b.b8, acc, 0, 0, 0);
        }
        __builtin_amdgcn_s_barrier();   // B4: window fully consumed
    }

    // ---------------- epilogue: D -> part
    #pragma unroll
    for (int r = 0; r < 16; ++r) {
        int m  = (r & 3) + 8 * (r >> 2) + 4 * kh;
        int nh = gh * 32 + m;
        int nn = nh >> 3, hh = nh & 7;
        part[((long)(blockIdx.x * 8 + nn)) * 2048 + hh * 256 + e0 + m32] = acc[r];
    }
    // se: gather A-build row-sums
    if (widx < 8) seLds[widx][lane] = rowsum;
    __syncthreads();
    if (widx == 0) {
        int ghb = lane >> 5, m = lane & 31;
        float s = 0.f;
        #pragma unroll
        for (int ks = 0; ks < 4; ++ks)
            s += seLds[ks * 2 + ghb][m] + seLds[ks * 2 + ghb][m + 32];
        int nn = lane >> 3, hh = lane & 7;
        pse[((long)(blockIdx.x * 8 + nn)) * 8 + hh] = s;
    }
}

// ---------------------------------------------------------------- k_epi (unchanged)
__global__ __launch_bounds__(256) void k_epi(const float* __restrict__ part,
                                             const float* __restrict__ pse,
                                             const float* __restrict__ W,
                                             const float* __restrict__ ib,
                                             const float* __restrict__ Wo,
                                             const float* __restrict__ ob,
                                             const float* __restrict__ gamma,
                                             const float* __restrict__ beta,
                                             float* __restrict__ out) {
    __shared__ float pn[2048];
    __shared__ float ses[8];
    __shared__ float ctx_s[256];
    __shared__ float r1[4], r2[4];
    int n = blockIdx.x & 7, b = blockIdx.x >> 3;
    int t = threadIdx.x;
    if (t < 8) {
        float s = 0.f;
        for (int chv = 0; chv < NCHB; ++chv)
            s += pse[(long)(b * 128 + chv * 8 + n) * 8 + t];
        ses[t] = s;
    }
    __syncthreads();
    bool has = ses[0] > 0.f;
    for (int j = 0; j < 8; ++j) {
        int idx = j * 256 + t;
        int h = idx >> 8;
        float s = 0.f;
        for (int chv = 0; chv < NCHB; ++chv)
            s += part[(long)(b * 128 + chv * 8 + n) * 2048 + idx];
        pn[idx] = has ? s / ses[h] : 0.f;
    }
    __syncthreads();
    int h = t >> 5;
    float c = ib[512 + t];
    {
        const float* wr = W + (long)(512 + t) * 256;
        const float* ph = pn + h * 256;
        for (int e = 0; e < 256; e += 4) {
            float4 wv4 = *(const float4*)(wr + e);
            float4 pv4 = *(const float4*)(ph + e);
            c += wv4.x * pv4.x + wv4.y * pv4.y + wv4.z * pv4.z + wv4.w * pv4.w;
        }
    }
    ctx_s[t] = c;
    __syncthreads();
    float o = ob[t];
    {
        const float* wr = Wo + (long)t * 256;
        for (int d = 0; d < 256; d += 4) {
            float4 wv4 = *(const float4*)(wr + d);
            float4 cv4 = *(const float4*)(ctx_s + d);
            o += wv4.x * cv4.x + wv4.y * cv4.y + wv4.z * cv4.z + wv4.w * cv4.w;
        }
    }
    float s1 = o, s2 = o * o;
    #pragma unroll
    for (int off = 32; off >= 1; off >>= 1) {
        s1 += __shfl_down(s1, off);
        s2 += __shfl_down(s2, off);
    }
    if ((t & 63) == 0) { r1[t >> 6] = s1; r2[t >> 6] = s2; }
    __syncthreads();
    float S1 = r1[0] + r1[1] + r1[2] + r1[3];
    float S2 = r2[0] + r2[1] + r2[2] + r2[3];
    float mu = S1 * (1.f / 256.f);
    float var = S2 * (1.f / 256.f) - mu * mu;
    float rr = rsqrtf(var + 1e-5f);
    float res = ((o - mu) * rr * gamma[t] + beta[t]) * (has ? 1.f : 0.f);
    out[((long)b * 8 + n) * 256 + t] = res;
}

// ---------------------------------------------------------------- launch
extern "C" void kernel_launch(void* const* d_in, const int* in_sizes, int n_in,
                              void* d_out, int out_size, void* d_ws, size_t ws_size,
                              hipStream_t stream) {
    const float* x     = (const float*)d_in[0];
    const float* query = (const float*)d_in[1];
    const float* W     = (const float*)d_in[2];
    const float* ib    = (const float*)d_in[3];
    const float* Wo    = (const float*)d_in[4];
    const float* ob    = (const float*)d_in[5];
    const float* gamma = (const float*)d_in[6];
    const float* beta  = (const float*)d_in[7];
    const unsigned char* mask = (const unsigned char*)d_in[8];
    const int* bid     = (const int*)d_in[9];
    float* out = (float*)d_out;
    float* ws  = (float*)d_ws;

    float* part = ws + OFF_PART;
    float* pse  = ws + OFF_PSE;

    k_setup<<<8, 256, 0, stream>>>(query, W, ib, ws);
    k_main<<<B_ * NCHB, 1024, 0, stream>>>(x, mask, bid, ws, part, pse);
    k_epi<<<B_ * NB_, 256, 0, stream>>>(part, pse, W, ib, Wo, ob, gamma, beta, out);
}